// Round 1
// baseline (1433.535 us; speedup 1.0000x reference)
//
#include <hip/hip_runtime.h>

// Linear SSM group scan, chunked parallel-scan decomposition (exact in fp32).
// Shapes: G=2, B=128, L=2048, S_D=64, I_D=16, O_D=16.
#define G_ 2
#define B_ 128
#define L_ 2048
#define SD 64
#define ID 16
#define OD 16
#define CH 8            // chunk length
#define NC (L_ / CH)    // 256 chunks
#define STATES_ELEMS (G_ * B_ * L_ * SD)  // 33554432
#define OBS_BASE STATES_ELEMS

typedef float v2 __attribute__((ext_vector_type(2)));

static __device__ __forceinline__ float readlane_f(float v, int lane) {
  return __builtin_bit_cast(float, __builtin_amdgcn_readlane(__builtin_bit_cast(int, v), lane));
}

// ---------------------------------------------------------------------------
// K0: compute F^8 per group via 3 squarings. Result written into the start of
// the observations region of d_out (consumed by k_scan, overwritten by
// k_phaseC afterwards).
// ---------------------------------------------------------------------------
__global__ void k_fpow(const float* __restrict__ Fm, float* __restrict__ fc) {
  __shared__ float M[SD * SD];
  const int g = blockIdx.x;
  const int t = threadIdx.x;  // 64 threads, one row each
  for (int s = 0; s < SD; ++s) M[t * SD + s] = Fm[(g * SD + t) * SD + s];
  __syncthreads();
  for (int it = 0; it < 3; ++it) {
    float row[SD];
#pragma unroll
    for (int cc = 0; cc < SD; ++cc) row[cc] = 0.f;
    for (int s = 0; s < SD; ++s) {
      const float a = M[t * SD + s];
#pragma unroll
      for (int cc = 0; cc < SD; ++cc) row[cc] += a * M[s * SD + cc];
    }
    __syncthreads();
#pragma unroll
    for (int cc = 0; cc < SD; ++cc) M[t * SD + cc] = row[cc];
    __syncthreads();
  }
  for (int cc = 0; cc < SD; ++cc) fc[g * SD * SD + t * SD + cc] = M[t * SD + cc];
}

// ---------------------------------------------------------------------------
// Phase A: per (g,b,chunk) thread, run the chunk recurrence from zero state,
// fusing the noise coloring (S_W) and input drive (B) on the fly.
// Stores only the chunk-final z into states[g,b,c*CH+CH-1,:] (a slot this
// chunk's phase-C thread will overwrite later; read by k_scan in between).
// Matrix operands are wave-uniform -> scalar loads; per-lane state in VGPRs.
// ---------------------------------------------------------------------------
__global__ __launch_bounds__(256, 1) void k_phaseA(
    const float* __restrict__ wn, const float* __restrict__ inp,
    const float* __restrict__ Fm, const float* __restrict__ Bm,
    const float* __restrict__ SW, float* __restrict__ states) {
  const int g = blockIdx.x >> 7;                       // 128 blocks per group
  const int item = ((blockIdx.x & 127) << 8) + threadIdx.x;  // 32768 per group
  const int b = item & (B_ - 1);                       // consecutive lanes = consecutive b
  const int c = item >> 7;                             // chunk id 0..255
  const float* Fg = Fm + g * SD * SD;
  const float* Wg = SW + g * SD * SD;
  const float* Bg = Bm + g * SD * ID;

  v2 z[SD / 2];
#pragma unroll
  for (int k = 0; k < SD / 2; ++k) { z[k].x = 0.f; z[k].y = 0.f; }

  for (int j = 0; j < CH; ++j) {
    const int l = c * CH + j;
    v2 w2[SD / 2];
    {
      const v2* wp = (const v2*)(wn + (((size_t)l * G_ + g) * B_ + b) * SD);
#pragma unroll
      for (int k = 0; k < SD / 2; ++k) w2[k] = wp[k];
    }
    v2 u2[ID / 2];
    {
      const v2* up = (const v2*)(inp + (((size_t)g * B_ + b) * L_ + l) * ID);
#pragma unroll
      for (int k = 0; k < ID / 2; ++k) u2[k] = up[k];
    }
    float zn[SD];
#pragma unroll
    for (int t = 0; t < SD; ++t) {
      const v2* fr = (const v2*)(Fg + t * SD);
      const v2* sr = (const v2*)(Wg + t * SD);
      const v2* br = (const v2*)(Bg + t * ID);
      v2 acc; acc.x = 0.f; acc.y = 0.f;
#pragma unroll
      for (int k = 0; k < SD / 2; ++k) acc += fr[k] * z[k] + sr[k] * w2[k];
#pragma unroll
      for (int k = 0; k < ID / 2; ++k) acc += br[k] * u2[k];
      zn[t] = acc.x + acc.y;
    }
#pragma unroll
    for (int k = 0; k < SD / 2; ++k) { z[k].x = zn[2 * k]; z[k].y = zn[2 * k + 1]; }
  }
  // write chunk-final z
  float4* zp = (float4*)(states + (((size_t)g * B_ + b) * L_ + c * CH + CH - 1) * SD);
#pragma unroll
  for (int q = 0; q < SD / 4; ++q) {
    float4 v;
    v.x = z[2 * q].x; v.y = z[2 * q].y; v.z = z[2 * q + 1].x; v.w = z[2 * q + 1].y;
    zp[q] = v;
  }
}

// ---------------------------------------------------------------------------
// Phase B: per-(g,b) sequential scan over chunk boundaries.
// init_{c+1} = F^8 * init_c + z_end_c. One wave per (g,b), lane = state dim.
// Writes init_c into states[g,b,c*CH,:] (read by phase C, then overwritten).
// Reads z_end from states[g,b,c*CH+CH-1,:] (written by phase A).
// ---------------------------------------------------------------------------
__global__ __launch_bounds__(64, 1) void k_scan(
    const float* __restrict__ s0, const float* __restrict__ fc,
    float* __restrict__ states) {
  const int gb = blockIdx.x;  // 0..255
  const int g = gb >> 7, b = gb & (B_ - 1);
  const int lane = threadIdx.x;  // = t
  float s = s0[(g * B_ + b) * SD + lane];
  float frow[SD];
  const float* fr = fc + (size_t)g * SD * SD + lane * SD;
#pragma unroll
  for (int k = 0; k < SD; ++k) frow[k] = fr[k];
  const size_t gbL = ((size_t)g * B_ + b) * L_;
  for (int c = 0; c < NC; ++c) {
    const size_t base = (gbL + c * CH) * SD;
    states[base + lane] = s;  // init_c
    const float zend = states[base + (size_t)(CH - 1) * SD + lane];
    float a0 = zend, a1 = 0.f, a2 = 0.f, a3 = 0.f;
#pragma unroll
    for (int k = 0; k < SD; k += 4) {
      a0 = fmaf(frow[k + 0], readlane_f(s, k + 0), a0);
      a1 = fmaf(frow[k + 1], readlane_f(s, k + 1), a1);
      a2 = fmaf(frow[k + 2], readlane_f(s, k + 2), a2);
      a3 = fmaf(frow[k + 3], readlane_f(s, k + 3), a3);
    }
    s = (a0 + a1) + (a2 + a3);
  }
}

// ---------------------------------------------------------------------------
// Phase C: per (g,b,chunk) thread, re-run the chunk from its true init
// (read from states[g,b,c*CH,:], written by k_scan), writing all states and
// observations. Exact same recurrence math as the reference.
// ---------------------------------------------------------------------------
__global__ __launch_bounds__(256, 1) void k_phaseC(
    const float* __restrict__ wn, const float* __restrict__ inp,
    const float* __restrict__ vn, const float* __restrict__ Fm,
    const float* __restrict__ Bm, const float* __restrict__ Hm,
    const float* __restrict__ SW, const float* __restrict__ SV,
    float* __restrict__ out) {
  const int g = blockIdx.x >> 7;
  const int item = ((blockIdx.x & 127) << 8) + threadIdx.x;
  const int b = item & (B_ - 1);
  const int c = item >> 7;
  const float* Fg = Fm + g * SD * SD;
  const float* Wg = SW + g * SD * SD;
  const float* Bg = Bm + g * SD * ID;
  const float* Hg = Hm + g * OD * SD;
  const float* Vg = SV + g * OD * OD;

  const size_t sbase = (((size_t)g * B_ + b) * L_ + (size_t)c * CH) * SD;
  const size_t obase = (size_t)OBS_BASE + (((size_t)g * B_ + b) * L_ + (size_t)c * CH) * OD;

  v2 z[SD / 2];
  {
    const v2* ip = (const v2*)(out + sbase);  // init_c (self-owned slot)
#pragma unroll
    for (int k = 0; k < SD / 2; ++k) z[k] = ip[k];
  }

  for (int j = 0; j < CH; ++j) {
    const int l = c * CH + j;
    v2 w2[SD / 2];
    {
      const v2* wp = (const v2*)(wn + (((size_t)l * G_ + g) * B_ + b) * SD);
#pragma unroll
      for (int k = 0; k < SD / 2; ++k) w2[k] = wp[k];
    }
    v2 u2[ID / 2];
    {
      const v2* up = (const v2*)(inp + (((size_t)g * B_ + b) * L_ + l) * ID);
#pragma unroll
      for (int k = 0; k < ID / 2; ++k) u2[k] = up[k];
    }
    v2 vv[OD / 2];
    {
      const v2* vp = (const v2*)(vn + (((size_t)l * G_ + g) * B_ + b) * OD);
#pragma unroll
      for (int k = 0; k < OD / 2; ++k) vv[k] = vp[k];
    }
    float zn[SD];
#pragma unroll
    for (int t = 0; t < SD; ++t) {
      const v2* fr = (const v2*)(Fg + t * SD);
      const v2* sr = (const v2*)(Wg + t * SD);
      const v2* br = (const v2*)(Bg + t * ID);
      v2 acc; acc.x = 0.f; acc.y = 0.f;
#pragma unroll
      for (int k = 0; k < SD / 2; ++k) acc += fr[k] * z[k] + sr[k] * w2[k];
#pragma unroll
      for (int k = 0; k < ID / 2; ++k) acc += br[k] * u2[k];
      zn[t] = acc.x + acc.y;
    }
#pragma unroll
    for (int k = 0; k < SD / 2; ++k) { z[k].x = zn[2 * k]; z[k].y = zn[2 * k + 1]; }

    // store state row (overwrites init slot at j==0, already consumed)
    float4* sp = (float4*)(out + sbase + (size_t)j * SD);
#pragma unroll
    for (int q = 0; q < SD / 4; ++q)
      sp[q] = make_float4(zn[4 * q], zn[4 * q + 1], zn[4 * q + 2], zn[4 * q + 3]);

    // observations: o[p] = H[p,:] . s_new + SV[p,:] . v
    float oo[OD];
#pragma unroll
    for (int p = 0; p < OD; ++p) {
      const v2* hr = (const v2*)(Hg + p * SD);
      const v2* vr = (const v2*)(Vg + p * OD);
      v2 acc; acc.x = 0.f; acc.y = 0.f;
#pragma unroll
      for (int k = 0; k < SD / 2; ++k) acc += hr[k] * z[k];
#pragma unroll
      for (int k = 0; k < OD / 2; ++k) acc += vr[k] * vv[k];
      oo[p] = acc.x + acc.y;
    }
    float4* op = (float4*)(out + obase + (size_t)j * OD);
#pragma unroll
    for (int q = 0; q < OD / 4; ++q)
      op[q] = make_float4(oo[4 * q], oo[4 * q + 1], oo[4 * q + 2], oo[4 * q + 3]);
  }
}

extern "C" void kernel_launch(void* const* d_in, const int* in_sizes, int n_in,
                              void* d_out, int out_size, void* d_ws, size_t ws_size,
                              hipStream_t stream) {
  const float* state0 = (const float*)d_in[0];
  const float* inputs = (const float*)d_in[1];
  const float* Fm     = (const float*)d_in[2];
  const float* Bm     = (const float*)d_in[3];
  const float* Hm     = (const float*)d_in[4];
  const float* SW     = (const float*)d_in[5];
  const float* SV     = (const float*)d_in[6];
  const float* wn     = (const float*)d_in[7];
  const float* vn     = (const float*)d_in[8];
  float* out = (float*)d_out;
  float* fc = out + OBS_BASE;  // F^8 staged at start of obs region

  k_fpow<<<G_, SD, 0, stream>>>(Fm, fc);
  k_phaseA<<<G_ * 128, 256, 0, stream>>>(wn, inputs, Fm, Bm, SW, out);
  k_scan<<<G_ * B_, SD, 0, stream>>>(state0, fc, out);
  k_phaseC<<<G_ * 128, 256, 0, stream>>>(wn, inputs, vn, Fm, Bm, Hm, SW, SV, out);
}

// Round 2
// 1145.505 us; speedup vs baseline: 1.2514x; 1.2514x over previous
//
#include <hip/hip_runtime.h>

// Linear SSM group scan: chunk-4 parallel phases + 2-level inter-chunk scan.
// G=2, B=128, L=2048, SD=64, ID=16, OD=16. All fp32, exact decomposition.
#define G_ 2
#define B_ 128
#define L_ 2048
#define SD 64
#define ID 16
#define OD 16
#define NC4 512
#define NC8 256
#define ROWW 144  // per-t LDS row: F(64) | SW(64) | B(16)
#define OBS_BASE ((size_t)(G_) * B_ * L_ * SD)

typedef float v2 __attribute__((ext_vector_type(2)));

static __device__ __forceinline__ size_t slotof(int g, int b, int l) {
  return (((size_t)g * B_ + b) * L_ + l) * (size_t)SD;
}
static __device__ __forceinline__ float rl(float v, int lane) {
  return __builtin_bit_cast(float, __builtin_amdgcn_readlane(__builtin_bit_cast(int, v), lane));
}
static __device__ __forceinline__ float load_sc0(const float* p) {
  return __hip_atomic_load(p, __ATOMIC_RELAXED, __HIP_MEMORY_SCOPE_AGENT);
}

// C = A*A (64x64), 256 threads. Caller syncs before and after.
static __device__ void lds_sq(const float* A, float* C, int tid) {
  const int r = tid & 63, q = tid >> 6;
  const float4* Ar = (const float4*)(A + r * SD);
  float acc[16];
#pragma unroll
  for (int c = 0; c < 16; ++c) acc[c] = 0.f;
#pragma unroll 1
  for (int k4 = 0; k4 < 16; ++k4) {
    float4 af = Ar[k4];
    const float* Bb = A + k4 * 4 * SD + q * 16;
#pragma unroll
    for (int kk = 0; kk < 4; ++kk) {
      float a = (kk == 0) ? af.x : (kk == 1) ? af.y : (kk == 2) ? af.z : af.w;
      const float4* Bk = (const float4*)(Bb + kk * SD);
#pragma unroll
      for (int c = 0; c < 4; ++c) {
        float4 bv = Bk[c];
        acc[4 * c + 0] = fmaf(a, bv.x, acc[4 * c + 0]);
        acc[4 * c + 1] = fmaf(a, bv.y, acc[4 * c + 1]);
        acc[4 * c + 2] = fmaf(a, bv.z, acc[4 * c + 2]);
        acc[4 * c + 3] = fmaf(a, bv.w, acc[4 * c + 3]);
      }
    }
  }
  float4* Cr = (float4*)(C + r * SD + q * 16);
#pragma unroll
  for (int c = 0; c < 4; ++c)
    Cr[c] = make_float4(acc[4 * c], acc[4 * c + 1], acc[4 * c + 2], acc[4 * c + 3]);
}

// ---------------------------------------------------------------------------
// kA: zero-init chunk-4 recurrence (fused noise coloring + input drive),
// streaming each step's state into its own slot (slot c4*4+3 = zend4 is the
// value later kernels consume; others are scratch until kC rewrites them).
// ---------------------------------------------------------------------------
__global__ __launch_bounds__(256, 2) void kA(
    const float* __restrict__ wn, const float* __restrict__ inp,
    const float* __restrict__ Fm, const float* __restrict__ Bm,
    const float* __restrict__ SW, float* __restrict__ out) {
  __shared__ __align__(16) float sM[SD * ROWW];
  const int tid = threadIdx.x;
  const int gblk = (int)(blockIdx.x >> 8);
  {
    const float* Fg = Fm + gblk * SD * SD;
    const float* Wg = SW + gblk * SD * SD;
    const float* Bg = Bm + gblk * SD * ID;
    for (int i = tid; i < SD * SD; i += 256) sM[(i >> 6) * ROWW + (i & 63)] = Fg[i];
    for (int i = tid; i < SD * SD; i += 256) sM[(i >> 6) * ROWW + 64 + (i & 63)] = Wg[i];
    for (int i = tid; i < SD * ID; i += 256) sM[(i >> 4) * ROWW + 128 + (i & 15)] = Bg[i];
  }
  __syncthreads();
  const int idx = (int)blockIdx.x * 256 + tid;
  const int b = idx & 127;
  const int rest = idx >> 7;
  const int c4 = rest & (NC4 - 1);
  const int g = rest >> 9;
  const int l0 = c4 * 4;
  float* myslot = out + slotof(g, b, l0);

  v2 z2[32];
#pragma unroll
  for (int k = 0; k < 32; ++k) z2[k] = (v2){0.f, 0.f};

#pragma unroll 1
  for (int j = 0; j < 4; ++j) {
    const int l = l0 + j;
    float4 w4[16];
    const float4* wp = (const float4*)(wn + (((size_t)l * G_ + g) * B_ + b) * SD);
#pragma unroll
    for (int q = 0; q < 16; ++q) w4[q] = wp[q];
    float4 u4[4];
    const float4* up = (const float4*)(inp + (((size_t)g * B_ + b) * L_ + l) * ID);
#pragma unroll
    for (int q = 0; q < 4; ++q) u4[q] = up[q];

    float* st = myslot + j * SD;
#pragma unroll 1
    for (int tg = 0; tg < 16; ++tg) {
      const float* mrow = sM + tg * 4 * ROWW;
      float zn[4];
#pragma unroll
      for (int i = 0; i < 4; ++i) {
        const float4* fr = (const float4*)(mrow + i * ROWW);
        const float4* sr = (const float4*)(mrow + i * ROWW + 64);
        const float4* br = (const float4*)(mrow + i * ROWW + 128);
        v2 acc = {0.f, 0.f};
#pragma unroll
        for (int q = 0; q < 16; ++q) {
          float4 f = fr[q];
          float4 s = sr[q];
          float4 w = w4[q];
          acc += (v2){f.x, f.y} * z2[2 * q] + (v2){f.z, f.w} * z2[2 * q + 1];
          acc += (v2){s.x, s.y} * (v2){w.x, w.y} + (v2){s.z, s.w} * (v2){w.z, w.w};
        }
#pragma unroll
        for (int q = 0; q < 4; ++q) {
          float4 bb = br[q];
          float4 u = u4[q];
          acc += (v2){bb.x, bb.y} * (v2){u.x, u.y} + (v2){bb.z, bb.w} * (v2){u.z, u.w};
        }
        zn[i] = acc.x + acc.y;
      }
      ((float4*)st)[tg] = make_float4(zn[0], zn[1], zn[2], zn[3]);
    }
    if (j != 3) {
      asm volatile("s_waitcnt vmcnt(0)" ::: "memory");
      const float4* rp = (const float4*)st;
#pragma unroll
      for (int q = 0; q < 16; ++q) {
        float4 v = rp[q];
        z2[2 * q] = (v2){v.x, v.y};
        z2[2 * q + 1] = (v2){v.z, v.w};
      }
    }
  }
}

// ---------------------------------------------------------------------------
// kB0: d(c8) = F^4 * zend4(2c8) + zend4(2c8+1)  -> slot c8*8+0
// ---------------------------------------------------------------------------
__global__ __launch_bounds__(256) void kB0(const float* __restrict__ Fm,
                                           float* __restrict__ out) {
  __shared__ __align__(16) float bufA[SD * SD];
  __shared__ __align__(16) float bufB[SD * SD];
  const int tid = threadIdx.x;
  const int idx = (int)blockIdx.x * 256 + tid;
  const int b = idx & 127;
  const int rest = idx >> 7;
  const int c8 = rest & (NC8 - 1);
  const int g = rest >> 8;
  {
    const float4* Fg = (const float4*)(Fm + g * SD * SD);
    float4* A4 = (float4*)bufA;
    for (int i = tid; i < SD * SD / 4; i += 256) A4[i] = Fg[i];
  }
  __syncthreads();
  lds_sq(bufA, bufB, tid);  __syncthreads();  // F^2
  lds_sq(bufB, bufA, tid);  __syncthreads();  // F^4 in bufA

  const float* za_p = out + slotof(g, b, c8 * 8 + 3);
  const float* zb_p = out + slotof(g, b, c8 * 8 + 7);
  float* d_p = out + slotof(g, b, c8 * 8);
  v2 x2[32];
  {
    const float4* xp = (const float4*)za_p;
#pragma unroll
    for (int q = 0; q < 16; ++q) {
      float4 f = xp[q];
      x2[2 * q] = (v2){f.x, f.y};
      x2[2 * q + 1] = (v2){f.z, f.w};
    }
  }
#pragma unroll 1
  for (int tg = 0; tg < 16; ++tg) {
    float4 zb4 = ((const float4*)zb_p)[tg];
    float zn[4];
#pragma unroll
    for (int i = 0; i < 4; ++i) {
      const float4* fr = (const float4*)(bufA + (tg * 4 + i) * SD);
      v2 acc = {0.f, 0.f};
#pragma unroll
      for (int q = 0; q < 16; ++q) {
        float4 f = fr[q];
        acc += (v2){f.x, f.y} * x2[2 * q] + (v2){f.z, f.w} * x2[2 * q + 1];
      }
      zn[i] = acc.x + acc.y + ((i == 0) ? zb4.x : (i == 1) ? zb4.y : (i == 2) ? zb4.z : zb4.w);
    }
    ((float4*)d_p)[tg] = make_float4(zn[0], zn[1], zn[2], zn[3]);
  }
}

// ---------------------------------------------------------------------------
// kB1: sequential chunk-8 scan. init8(c8+1) = F^8*init8(c8) + d(c8).
// Stores init8(c8) into slot c8*8 (overwriting d after consumption).
// One wave per (g,b); lane = state dim.
// ---------------------------------------------------------------------------
__global__ __launch_bounds__(256) void kB1(const float* __restrict__ Fm,
                                           const float* __restrict__ s0,
                                           float* __restrict__ out) {
  __shared__ __align__(16) float bufA[SD * SD];
  __shared__ __align__(16) float bufB[SD * SD];
  const int tid = threadIdx.x;
  const int gb = (int)blockIdx.x * 4 + (tid >> 6);
  const int g = gb >> 7, b = gb & 127;
  const int lane = tid & 63;
  {
    const int gg = ((int)blockIdx.x * 4) >> 7;  // uniform per block
    const float4* Fg = (const float4*)(Fm + gg * SD * SD);
    float4* A4 = (float4*)bufA;
    for (int i = tid; i < SD * SD / 4; i += 256) A4[i] = Fg[i];
  }
  __syncthreads();
  lds_sq(bufA, bufB, tid);  __syncthreads();  // F^2
  lds_sq(bufB, bufA, tid);  __syncthreads();  // F^4
  lds_sq(bufA, bufB, tid);  __syncthreads();  // F^8 in bufB

  float frow[SD];
  const float4* Fr = (const float4*)(bufB + lane * SD);
#pragma unroll
  for (int i = 0; i < 16; ++i) {
    float4 f = Fr[i];
    frow[4 * i] = f.x; frow[4 * i + 1] = f.y; frow[4 * i + 2] = f.z; frow[4 * i + 3] = f.w;
  }
  float s = s0[(g * B_ + b) * SD + lane];
  float dcur = out[slotof(g, b, 0) + lane];
  float dnext = out[slotof(g, b, 8) + lane];
#pragma unroll 1
  for (int c8 = 0; c8 < NC8; ++c8) {
    asm volatile("s_waitcnt vmcnt(0)" ::: "memory");  // dcur/dnext/dpf resident
    out[slotof(g, b, c8 * 8) + lane] = s;             // init8(c8); d(c8) already in regs
    const int cn = (c8 + 2 < NC8) ? c8 + 2 : NC8 - 1;
    float dpf = out[slotof(g, b, cn * 8) + lane];
    float a0 = dcur, a1 = 0.f, a2 = 0.f, a3 = 0.f;
#pragma unroll
    for (int k = 0; k < SD; k += 4) {
      a0 = fmaf(frow[k + 0], rl(s, k + 0), a0);
      a1 = fmaf(frow[k + 1], rl(s, k + 1), a1);
      a2 = fmaf(frow[k + 2], rl(s, k + 2), a2);
      a3 = fmaf(frow[k + 3], rl(s, k + 3), a3);
    }
    s = (a0 + a1) + (a2 + a3);
    dcur = dnext;
    dnext = dpf;
  }
}

// ---------------------------------------------------------------------------
// kB2: odd chunk-4 inits: init4(2c8+1) = F^4*init8(c8) + zend4(2c8) -> slot c8*8+4
// ---------------------------------------------------------------------------
__global__ __launch_bounds__(256) void kB2(const float* __restrict__ Fm,
                                           float* __restrict__ out) {
  __shared__ __align__(16) float bufA[SD * SD];
  __shared__ __align__(16) float bufB[SD * SD];
  const int tid = threadIdx.x;
  const int idx = (int)blockIdx.x * 256 + tid;
  const int b = idx & 127;
  const int rest = idx >> 7;
  const int c8 = rest & (NC8 - 1);
  const int g = rest >> 8;
  {
    const float4* Fg = (const float4*)(Fm + g * SD * SD);
    float4* A4 = (float4*)bufA;
    for (int i = tid; i < SD * SD / 4; i += 256) A4[i] = Fg[i];
  }
  __syncthreads();
  lds_sq(bufA, bufB, tid);  __syncthreads();
  lds_sq(bufB, bufA, tid);  __syncthreads();  // F^4 in bufA

  const float* x_p = out + slotof(g, b, c8 * 8);       // init8(c8)
  const float* zb_p = out + slotof(g, b, c8 * 8 + 3);  // zend4(2c8)
  float* o_p = out + slotof(g, b, c8 * 8 + 4);
  v2 x2[32];
  {
    const float4* xp = (const float4*)x_p;
#pragma unroll
    for (int q = 0; q < 16; ++q) {
      float4 f = xp[q];
      x2[2 * q] = (v2){f.x, f.y};
      x2[2 * q + 1] = (v2){f.z, f.w};
    }
  }
#pragma unroll 1
  for (int tg = 0; tg < 16; ++tg) {
    float4 zb4 = ((const float4*)zb_p)[tg];
    float zn[4];
#pragma unroll
    for (int i = 0; i < 4; ++i) {
      const float4* fr = (const float4*)(bufA + (tg * 4 + i) * SD);
      v2 acc = {0.f, 0.f};
#pragma unroll
      for (int q = 0; q < 16; ++q) {
        float4 f = fr[q];
        acc += (v2){f.x, f.y} * x2[2 * q] + (v2){f.z, f.w} * x2[2 * q + 1];
      }
      zn[i] = acc.x + acc.y + ((i == 0) ? zb4.x : (i == 1) ? zb4.y : (i == 2) ? zb4.z : zb4.w);
    }
    ((float4*)o_p)[tg] = make_float4(zn[0], zn[1], zn[2], zn[3]);
  }
}

// ---------------------------------------------------------------------------
// kC: true chunk-4 recurrence from init (slot l0, sc0 load), streaming states
// into their slots, plus observations after each step's reload.
// ---------------------------------------------------------------------------
__global__ __launch_bounds__(256, 2) void kC(
    const float* __restrict__ wn, const float* __restrict__ inp,
    const float* __restrict__ vn, const float* __restrict__ Fm,
    const float* __restrict__ Bm, const float* __restrict__ Hm,
    const float* __restrict__ SW, const float* __restrict__ SV,
    float* __restrict__ out) {
  __shared__ __align__(16) float sM[SD * ROWW];
  __shared__ __align__(16) float sHV[OD * 80];
  const int tid = threadIdx.x;
  const int gblk = (int)(blockIdx.x >> 8);
  {
    const float* Fg = Fm + gblk * SD * SD;
    const float* Wg = SW + gblk * SD * SD;
    const float* Bg = Bm + gblk * SD * ID;
    const float* Hg = Hm + gblk * OD * SD;
    const float* Vg = SV + gblk * OD * OD;
    for (int i = tid; i < SD * SD; i += 256) sM[(i >> 6) * ROWW + (i & 63)] = Fg[i];
    for (int i = tid; i < SD * SD; i += 256) sM[(i >> 6) * ROWW + 64 + (i & 63)] = Wg[i];
    for (int i = tid; i < SD * ID; i += 256) sM[(i >> 4) * ROWW + 128 + (i & 15)] = Bg[i];
    for (int i = tid; i < OD * SD; i += 256) sHV[(i >> 6) * 80 + (i & 63)] = Hg[i];
    for (int i = tid; i < OD * OD; i += 256) sHV[(i >> 4) * 80 + 64 + (i & 15)] = Vg[i];
  }
  __syncthreads();
  const int idx = (int)blockIdx.x * 256 + tid;
  const int b = idx & 127;
  const int rest = idx >> 7;
  const int c4 = rest & (NC4 - 1);
  const int g = rest >> 9;
  const int l0 = c4 * 4;
  float* myslot = out + slotof(g, b, l0);
  float* myobs = out + OBS_BASE + (((size_t)g * B_ + b) * L_ + l0) * OD;

  v2 z2[32];
  {
    const float* ip = myslot;  // init4(c4), written by kB1 (even) / kB2 (odd)
#pragma unroll
    for (int k = 0; k < 32; ++k)
      z2[k] = (v2){load_sc0(ip + 2 * k), load_sc0(ip + 2 * k + 1)};
  }
#pragma unroll 1
  for (int j = 0; j < 4; ++j) {
    const int l = l0 + j;
    float4 w4[16];
    const float4* wp = (const float4*)(wn + (((size_t)l * G_ + g) * B_ + b) * SD);
#pragma unroll
    for (int q = 0; q < 16; ++q) w4[q] = wp[q];
    float4 u4[4];
    const float4* up = (const float4*)(inp + (((size_t)g * B_ + b) * L_ + l) * ID);
#pragma unroll
    for (int q = 0; q < 4; ++q) u4[q] = up[q];

    float* st = myslot + j * SD;
#pragma unroll 1
    for (int tg = 0; tg < 16; ++tg) {
      const float* mrow = sM + tg * 4 * ROWW;
      float zn[4];
#pragma unroll
      for (int i = 0; i < 4; ++i) {
        const float4* fr = (const float4*)(mrow + i * ROWW);
        const float4* sr = (const float4*)(mrow + i * ROWW + 64);
        const float4* br = (const float4*)(mrow + i * ROWW + 128);
        v2 acc = {0.f, 0.f};
#pragma unroll
        for (int q = 0; q < 16; ++q) {
          float4 f = fr[q];
          float4 s = sr[q];
          float4 w = w4[q];
          acc += (v2){f.x, f.y} * z2[2 * q] + (v2){f.z, f.w} * z2[2 * q + 1];
          acc += (v2){s.x, s.y} * (v2){w.x, w.y} + (v2){s.z, s.w} * (v2){w.z, w.w};
        }
#pragma unroll
        for (int q = 0; q < 4; ++q) {
          float4 bb = br[q];
          float4 u = u4[q];
          acc += (v2){bb.x, bb.y} * (v2){u.x, u.y} + (v2){bb.z, bb.w} * (v2){u.z, u.w};
        }
        zn[i] = acc.x + acc.y;
      }
      ((float4*)st)[tg] = make_float4(zn[0], zn[1], zn[2], zn[3]);
    }
    float4 v4[4];
    const float4* vp = (const float4*)(vn + (((size_t)l * G_ + g) * B_ + b) * OD);
#pragma unroll
    for (int q = 0; q < 4; ++q) v4[q] = vp[q];

    asm volatile("s_waitcnt vmcnt(0)" ::: "memory");
    const float4* rp = (const float4*)st;
#pragma unroll
    for (int q = 0; q < 16; ++q) {
      float4 v = rp[q];
      z2[2 * q] = (v2){v.x, v.y};
      z2[2 * q + 1] = (v2){v.z, v.w};
    }
    // observations
#pragma unroll 1
    for (int og = 0; og < 4; ++og) {
      float oo[4];
#pragma unroll
      for (int i = 0; i < 4; ++i) {
        const int p = og * 4 + i;
        const float4* hr = (const float4*)(sHV + p * 80);
        const float4* vr = (const float4*)(sHV + p * 80 + 64);
        v2 acc = {0.f, 0.f};
#pragma unroll
        for (int q = 0; q < 16; ++q) {
          float4 h = hr[q];
          acc += (v2){h.x, h.y} * z2[2 * q] + (v2){h.z, h.w} * z2[2 * q + 1];
        }
#pragma unroll
        for (int q = 0; q < 4; ++q) {
          float4 sv = vr[q];
          float4 vv = v4[q];
          acc += (v2){sv.x, sv.y} * (v2){vv.x, vv.y} + (v2){sv.z, sv.w} * (v2){vv.z, vv.w};
        }
        oo[i] = acc.x + acc.y;
      }
      ((float4*)(myobs + j * OD))[og] = make_float4(oo[0], oo[1], oo[2], oo[3]);
    }
  }
}

extern "C" void kernel_launch(void* const* d_in, const int* in_sizes, int n_in,
                              void* d_out, int out_size, void* d_ws, size_t ws_size,
                              hipStream_t stream) {
  (void)in_sizes; (void)n_in; (void)out_size; (void)d_ws; (void)ws_size;
  const float* state0 = (const float*)d_in[0];
  const float* inputs = (const float*)d_in[1];
  const float* Fm     = (const float*)d_in[2];
  const float* Bm     = (const float*)d_in[3];
  const float* Hm     = (const float*)d_in[4];
  const float* SW     = (const float*)d_in[5];
  const float* SV     = (const float*)d_in[6];
  const float* wn     = (const float*)d_in[7];
  const float* vn     = (const float*)d_in[8];
  float* out = (float*)d_out;

  kA<<<512, 256, 0, stream>>>(wn, inputs, Fm, Bm, SW, out);
  kB0<<<256, 256, 0, stream>>>(Fm, out);
  kB1<<<64, 256, 0, stream>>>(Fm, state0, out);
  kB2<<<256, 256, 0, stream>>>(Fm, out);
  kC<<<512, 256, 0, stream>>>(wn, inputs, vn, Fm, Bm, Hm, SW, SV, out);
}